// Round 2
// baseline (689.280 us; speedup 1.0000x reference)
//
#include <hip/hip_runtime.h>
#include <math.h>

// Problem constants (from reference setup_inputs)
#define NHEADS 4
#define HD     32           // head dim
#define WSP    7            // split size (window width)
#define NWINW  16           // windows per image (W / WSP)
#define HH     112
#define WWID   112
#define BB     4
#define LL     (HH*WWID)    // 12544 tokens per image
#define CC     128
#define NTOK   (HH*WSP)     // 784 tokens per window
#define QT     64
#define KT     64
#define NQT    13           // ceil(784/64)
#define NKT    13

// LDS row strides (floats), padded against bank conflicts, 16B-aligned rows
#define QS 36
#define PS 68

__global__ __launch_bounds__(256)
void attn_kernel(const float* __restrict__ qkv, float* __restrict__ out) {
    const int qt = blockIdx.x;        // q tile 0..12
    const int wh = blockIdx.y;        // 0..255 : ((b*16+wi)*4 + h)
    const int h  = wh & 3;
    const int bw = wh >> 2;
    const int b  = bw >> 4;
    const int wi = bw & 15;

    const int tid = threadIdx.x;
    const int rg  = tid >> 4;         // row group 0..15, owns q-rows rg*4+i
    const int cg  = tid & 15;         // col id 0..15, owns k-cols cg+16*j

    __shared__ float Qs[QT][QS];
    __shared__ float Ks[KT][QS];
    __shared__ float Vs[KT][QS];
    __shared__ float Ps[QT][PS];

    const size_t plane = (size_t)BB * LL * CC;
    const float* qp = qkv + (size_t)b * LL * CC;
    const float* kp = qp + plane;
    const float* vp = qp + 2 * plane;
    const int chbase = h * HD;

    // ---- stage Q tile (zeros for rows past NTOK) ----
    {
        const int r0 = tid >> 3;           // 0..31
        const int c4 = (tid & 7) * 4;
        #pragma unroll
        for (int pass = 0; pass < 2; ++pass) {
            const int r  = r0 + pass * 32;
            const int qg = qt * QT + r;
            float4 val = make_float4(0.f, 0.f, 0.f, 0.f);
            if (qg < NTOK) {
                const int l = (qg / WSP) * WWID + wi * WSP + (qg % WSP);
                val = *(const float4*)(qp + (size_t)l * CC + chbase + c4);
            }
            *(float4*)&Qs[r][c4] = val;
        }
    }

    float m_i[4], l_i[4], acc[4][2];
    #pragma unroll
    for (int i = 0; i < 4; ++i) {
        m_i[i] = -INFINITY; l_i[i] = 0.f;
        acc[i][0] = 0.f; acc[i][1] = 0.f;
    }

    const float scale = 0.17677669529663687f;   // 32^-0.5

    for (int kt_i = 0; kt_i < NKT; ++kt_i) {
        __syncthreads();   // protect Ks/Vs from previous iteration's readers
        // ---- stage K,V tile ----
        {
            const int r0 = tid >> 3;
            const int c4 = (tid & 7) * 4;
            #pragma unroll
            for (int pass = 0; pass < 2; ++pass) {
                const int r  = r0 + pass * 32;
                const int kg = kt_i * KT + r;
                float4 kval = make_float4(0.f, 0.f, 0.f, 0.f);
                float4 vval = make_float4(0.f, 0.f, 0.f, 0.f);
                if (kg < NTOK) {
                    const int l = (kg / WSP) * WWID + wi * WSP + (kg % WSP);
                    kval = *(const float4*)(kp + (size_t)l * CC + chbase + c4);
                    vval = *(const float4*)(vp + (size_t)l * CC + chbase + c4);
                }
                *(float4*)&Ks[r][c4] = kval;
                *(float4*)&Vs[r][c4] = vval;
            }
        }
        __syncthreads();

        // ---- S = Q K^T (4x4 micro-tile), cols cg+16*j ----
        float s[4][4];
        #pragma unroll
        for (int i = 0; i < 4; ++i)
            #pragma unroll
            for (int j = 0; j < 4; ++j) s[i][j] = 0.f;

        #pragma unroll
        for (int dq = 0; dq < HD; dq += 4) {
            float4 qv[4], kv[4];
            #pragma unroll
            for (int i = 0; i < 4; ++i) qv[i] = *(const float4*)&Qs[rg * 4 + i][dq];
            #pragma unroll
            for (int j = 0; j < 4; ++j) kv[j] = *(const float4*)&Ks[cg + 16 * j][dq];
            #pragma unroll
            for (int i = 0; i < 4; ++i)
                #pragma unroll
                for (int j = 0; j < 4; ++j)
                    s[i][j] += qv[i].x * kv[j].x + qv[i].y * kv[j].y
                             + qv[i].z * kv[j].z + qv[i].w * kv[j].w;
        }

        // scale + k-mask
        #pragma unroll
        for (int j = 0; j < 4; ++j) {
            const int kg = kt_i * KT + cg + 16 * j;
            #pragma unroll
            for (int i = 0; i < 4; ++i)
                s[i][j] = (kg < NTOK) ? s[i][j] * scale : -INFINITY;
        }

        // row max over 64 cols (4 local + shfl over 16 lanes)
        float rmax[4];
        #pragma unroll
        for (int i = 0; i < 4; ++i)
            rmax[i] = fmaxf(fmaxf(s[i][0], s[i][1]), fmaxf(s[i][2], s[i][3]));
        #pragma unroll
        for (int mk = 1; mk < 16; mk <<= 1)
            #pragma unroll
            for (int i = 0; i < 4; ++i)
                rmax[i] = fmaxf(rmax[i], __shfl_xor(rmax[i], mk, 16));

        float pscale[4];
        #pragma unroll
        for (int i = 0; i < 4; ++i) {
            const float mnew = fmaxf(m_i[i], rmax[i]);
            pscale[i] = __expf(m_i[i] - mnew);
            m_i[i] = mnew;
        }

        // P = exp(s - m), row sums
        float rsum[4];
        #pragma unroll
        for (int i = 0; i < 4; ++i) {
            rsum[i] = 0.f;
            #pragma unroll
            for (int j = 0; j < 4; ++j) {
                const float p = __expf(s[i][j] - m_i[i]);
                s[i][j] = p;
                rsum[i] += p;
            }
        }
        #pragma unroll
        for (int mk = 1; mk < 16; mk <<= 1)
            #pragma unroll
            for (int i = 0; i < 4; ++i)
                rsum[i] += __shfl_xor(rsum[i], mk, 16);
        #pragma unroll
        for (int i = 0; i < 4; ++i) {
            l_i[i] = l_i[i] * pscale[i] + rsum[i];
            acc[i][0] *= pscale[i];
            acc[i][1] *= pscale[i];
        }

        // write P to LDS (rows wave-private -> no barrier needed before read)
        #pragma unroll
        for (int i = 0; i < 4; ++i)
            #pragma unroll
            for (int j = 0; j < 4; ++j)
                Ps[rg * 4 + i][cg + 16 * j] = s[i][j];

        // ---- PV: acc[q][d] += sum_k P[q][k] * V[k][d], d = cg*2 + {0,1} ----
        #pragma unroll
        for (int kq = 0; kq < KT; kq += 4) {
            float4 p_[4];
            #pragma unroll
            for (int i = 0; i < 4; ++i) p_[i] = *(const float4*)&Ps[rg * 4 + i][kq];
            float2 v_[4];
            #pragma unroll
            for (int j = 0; j < 4; ++j) v_[j] = *(const float2*)&Vs[kq + j][cg * 2];
            #pragma unroll
            for (int i = 0; i < 4; ++i) {
                acc[i][0] += p_[i].x * v_[0].x + p_[i].y * v_[1].x
                           + p_[i].z * v_[2].x + p_[i].w * v_[3].x;
                acc[i][1] += p_[i].x * v_[0].y + p_[i].y * v_[1].y
                           + p_[i].z * v_[2].y + p_[i].w * v_[3].y;
            }
        }
    }

    // ---- epilogue: out = acc / l ----
    #pragma unroll
    for (int i = 0; i < 4; ++i) {
        const int qg = qt * QT + rg * 4 + i;
        if (qg < NTOK) {
            const float inv = 1.0f / l_i[i];
            const int l = (qg / WSP) * WWID + wi * WSP + (qg % WSP);
            float2 o = make_float2(acc[i][0] * inv, acc[i][1] * inv);
            *(float2*)(out + ((size_t)b * LL + l) * CC + chbase + cg * 2) = o;
        }
    }
}

// Depthwise 3x3 SAME conv over each 112x7 window image of V; out += conv + bias.
__global__ __launch_bounds__(256)
void lepe_kernel(const float* __restrict__ qkv, const float* __restrict__ cw,
                 const float* __restrict__ cb, float* __restrict__ out) {
    const size_t idx = (size_t)blockIdx.x * 256 + threadIdx.x;
    if (idx >= (size_t)BB * LL * CC) return;
    const int ch = (int)(idx & (CC - 1));
    const size_t rest = idx >> 7;
    const int l = (int)(rest % LL);
    const int b = (int)(rest / LL);
    const int hr = l / WWID, col = l % WWID;
    const int wi = col / WSP, wc = col % WSP;

    const float* vp = qkv + 2 * (size_t)BB * LL * CC + (size_t)b * LL * CC;
    float acc = cb[ch];
    #pragma unroll
    for (int dy = -1; dy <= 1; ++dy) {
        const int y = hr + dy;
        if (y < 0 || y >= HH) continue;
        #pragma unroll
        for (int dx = -1; dx <= 1; ++dx) {
            const int x = wc + dx;
            if (x < 0 || x >= WSP) continue;   // window-local zero padding
            const int ln = y * WWID + wi * WSP + x;
            acc += cw[ch * 9 + (dy + 1) * 3 + (dx + 1)] * vp[(size_t)ln * CC + ch];
        }
    }
    out[idx] += acc;
}

extern "C" void kernel_launch(void* const* d_in, const int* in_sizes, int n_in,
                              void* d_out, int out_size, void* d_ws, size_t ws_size,
                              hipStream_t stream) {
    const float* qkv = (const float*)d_in[0];
    const float* cw  = (const float*)d_in[1];
    const float* cb  = (const float*)d_in[2];
    float* out = (float*)d_out;

    dim3 grid(NQT, 256);
    attn_kernel<<<grid, 256, 0, stream>>>(qkv, out);

    const size_t total = (size_t)BB * LL * CC;
    lepe_kernel<<<(int)((total + 255) / 256), 256, 0, stream>>>(qkv, cw, cb, out);
}

// Round 3
// 441.751 us; speedup vs baseline: 1.5603x; 1.5603x over previous
//
#include <hip/hip_runtime.h>
#include <math.h>

#define NHEADS 4
#define HD     32
#define WSP    7
#define HH     112
#define WWID   112
#define BB     4
#define LL     (HH*WWID)     // 12544
#define CC     128
#define NTOK   (HH*WSP)      // 784
#define QTILE  64
#define NKT    13            // ceil(784/64), padded to 832
#define NQT    13
#define TMAX   832

typedef __attribute__((ext_vector_type(8))) short bf16x8;
typedef __attribute__((ext_vector_type(4))) float f32x4;

__device__ inline short f2bf(float x) {
    unsigned u = __builtin_bit_cast(unsigned, x);
    unsigned r = (u + 0x7fffu + ((u >> 16) & 1u)) >> 16;
    return (short)r;
}
__device__ inline float bf2f(short h) {
    unsigned u = ((unsigned)(unsigned short)h) << 16;
    return __builtin_bit_cast(float, u);
}

__global__ __launch_bounds__(256)
void attn_mfma(const float* __restrict__ qkv, float* __restrict__ out) {
    const int qt = blockIdx.x;       // q tile 0..12
    const int wh = blockIdx.y;       // ((b*16+wi)*4 + h)
    const int h  = wh & 3;
    const int bw = wh >> 2;
    const int b  = bw >> 4;
    const int wi = bw & 15;

    const int tid  = threadIdx.x;
    const int w    = tid >> 6;       // wave 0..3, owns q-rows w*16..w*16+15
    const int lane = tid & 63;
    const int g    = lane >> 4;      // 0..3
    const int c    = lane & 15;

    __shared__ __align__(16) short Pl[4][16 * 64];  // per-wave P (bf16), swizzled
    __shared__ int l_tab[TMAX];                     // token -> row-base float offset (*CC)

    // build token->offset table (clamped), one barrier total
    for (int t = tid; t < TMAX; t += 256) {
        int tc = t < NTOK ? t : NTOK - 1;
        l_tab[t] = ((tc / 7) * WWID + wi * WSP + (tc % 7)) * CC;
    }
    __syncthreads();

    const size_t plane = (size_t)BB * LL * CC;
    const float* qp = qkv + (size_t)b * LL * CC;
    const float* kp = qp + plane;
    const float* vp = qp + 2 * plane;
    const int chb = h * HD;

    // ---- Q A-frag (hi/lo), scale folded in ----
    bf16x8 qh, ql;
    {
        const int qrow = qt * QTILE + w * 16 + c;   // <= 831
        const float* p = qp + l_tab[qrow] + chb + g * 8;
        float4 a0 = *(const float4*)p;
        float4 a1 = *(const float4*)(p + 4);
        float av[8] = {a0.x, a0.y, a0.z, a0.w, a1.x, a1.y, a1.z, a1.w};
        const float scale = 0.17677669529663687f;   // 32^-0.5
        #pragma unroll
        for (int j = 0; j < 8; ++j) {
            float x = av[j] * scale;
            short hi = f2bf(x);
            qh[j] = hi;
            ql[j] = f2bf(x - bf2f(hi));
        }
    }

    const bf16x8 ones = {(short)0x3F80, (short)0x3F80, (short)0x3F80, (short)0x3F80,
                         (short)0x3F80, (short)0x3F80, (short)0x3F80, (short)0x3F80};

    float m_r[4];
    f32x4 acc0 = {0.f, 0.f, 0.f, 0.f};
    f32x4 acc1 = {0.f, 0.f, 0.f, 0.f};
    f32x4 accl = {0.f, 0.f, 0.f, 0.f};
    #pragma unroll
    for (int r = 0; r < 4; ++r) m_r[r] = -INFINITY;

    short* pb = &Pl[w][0];

    for (int kt = 0; kt < NKT; ++kt) {
        // ---- K B-frags (hi/lo), direct global->reg ----
        bf16x8 kh[4], kl[4];
        #pragma unroll
        for (int f = 0; f < 4; ++f) {
            const int t = kt * 64 + f * 16 + c;
            const float* p = kp + l_tab[t] + chb + g * 8;
            float4 a0 = *(const float4*)p;
            float4 a1 = *(const float4*)(p + 4);
            float av[8] = {a0.x, a0.y, a0.z, a0.w, a1.x, a1.y, a1.z, a1.w};
            #pragma unroll
            for (int j = 0; j < 8; ++j) {
                short hi = f2bf(av[j]);
                kh[f][j] = hi;
                kl[f][j] = f2bf(av[j] - bf2f(hi));
            }
        }

        // ---- S = Q K^T : 3 MFMAs per 16-key group (hi/lo split) ----
        f32x4 sf[4];
        #pragma unroll
        for (int f = 0; f < 4; ++f) {
            f32x4 z = {0.f, 0.f, 0.f, 0.f};
            z = __builtin_amdgcn_mfma_f32_16x16x32_bf16(qh, kh[f], z, 0, 0, 0);
            z = __builtin_amdgcn_mfma_f32_16x16x32_bf16(qh, kl[f], z, 0, 0, 0);
            sf[f] = __builtin_amdgcn_mfma_f32_16x16x32_bf16(ql, kh[f], z, 0, 0, 0);
        }

        // mask invalid keys
        #pragma unroll
        for (int f = 0; f < 4; ++f) {
            const int key = kt * 64 + f * 16 + c;
            if (key >= NTOK) {
                sf[f][0] = -INFINITY; sf[f][1] = -INFINITY;
                sf[f][2] = -INFINITY; sf[f][3] = -INFINITY;
            }
        }

        // row max: local over 4 frags, then shfl-xor over 16 lanes
        float rmax[4];
        #pragma unroll
        for (int r = 0; r < 4; ++r)
            rmax[r] = fmaxf(fmaxf(sf[0][r], sf[1][r]), fmaxf(sf[2][r], sf[3][r]));
        #pragma unroll
        for (int mk = 1; mk < 16; mk <<= 1)
            #pragma unroll
            for (int r = 0; r < 4; ++r)
                rmax[r] = fmaxf(rmax[r], __shfl_xor(rmax[r], mk, 16));

        float psc[4];
        #pragma unroll
        for (int r = 0; r < 4; ++r) {
            const float mn = fmaxf(m_r[r], rmax[r]);
            psc[r] = __expf(m_r[r] - mn);
            m_r[r] = mn;
        }

        // P = exp(S - m)
        #pragma unroll
        for (int f = 0; f < 4; ++f)
            #pragma unroll
            for (int r = 0; r < 4; ++r)
                sf[f][r] = __expf(sf[f][r] - m_r[r]);

        // rescale accumulators
        #pragma unroll
        for (int r = 0; r < 4; ++r) {
            acc0[r] *= psc[r];
            acc1[r] *= psc[r];
            accl[r] *= psc[r];
        }

        // ---- write P (bf16) to wave-private LDS, XOR-swizzled ----
        #pragma unroll
        for (int f = 0; f < 4; ++f)
            #pragma unroll
            for (int r = 0; r < 4; ++r) {
                const int row = g * 4 + r;
                const int off = (f * 16 + c) * 2;
                pb[(row * 128 + (off ^ ((row & 7) << 4))) >> 1] = f2bf(sf[f][r]);
            }

        // ---- PV: A = P (from LDS), B = V (hi/lo, direct global) ----
        #pragma unroll
        for (int s = 0; s < 2; ++s) {
            const int offr = s * 64 + g * 16;
            bf16x8 pa = *(const bf16x8*)&pb[(c * 128 + (offr ^ ((c & 7) << 4))) >> 1];

            const int tbase = kt * 64 + s * 32 + g * 8;
            #pragma unroll
            for (int cb = 0; cb < 2; ++cb) {
                bf16x8 vh, vl;
                #pragma unroll
                for (int j = 0; j < 8; ++j) {
                    const float x = vp[l_tab[tbase + j] + chb + cb * 16 + c];
                    short hi = f2bf(x);
                    vh[j] = hi;
                    vl[j] = f2bf(x - bf2f(hi));
                }
                if (cb == 0) {
                    acc0 = __builtin_amdgcn_mfma_f32_16x16x32_bf16(pa, vh, acc0, 0, 0, 0);
                    acc0 = __builtin_amdgcn_mfma_f32_16x16x32_bf16(pa, vl, acc0, 0, 0, 0);
                } else {
                    acc1 = __builtin_amdgcn_mfma_f32_16x16x32_bf16(pa, vh, acc1, 0, 0, 0);
                    acc1 = __builtin_amdgcn_mfma_f32_16x16x32_bf16(pa, vl, acc1, 0, 0, 0);
                }
            }
            accl = __builtin_amdgcn_mfma_f32_16x16x32_bf16(pa, ones, accl, 0, 0, 0);
        }
    }

    // ---- epilogue: out = acc / l  (rows g*4+r, ch = chb + cb*16 + c) ----
    #pragma unroll
    for (int r = 0; r < 4; ++r) {
        const int qrow = qt * QTILE + w * 16 + g * 4 + r;
        if (qrow < NTOK) {
            const float inv = 1.0f / accl[r];
            float* o = out + (size_t)b * LL * CC + l_tab[qrow] + chb;
            o[c]      = acc0[r] * inv;
            o[16 + c] = acc1[r] * inv;
        }
    }
}

// Depthwise 3x3 SAME conv over each 112x7 window image of V; out += conv + bias.
// float4 across channels.
__global__ __launch_bounds__(256)
void lepe2(const float* __restrict__ qkv, const float* __restrict__ cw,
           const float* __restrict__ cbv, float* __restrict__ out) {
    const int t = blockIdx.x * 256 + threadIdx.x;
    if (t >= BB * LL * (CC / 4)) return;
    const int c4   = (t & 31) * 4;
    const int rest = t >> 5;               // b*LL + l
    const int l = rest % LL, b = rest / LL;
    const int hr = l / WWID, col = l % WWID;
    const int wi = col / WSP, wc = col - wi * WSP;

    const float* vp = qkv + 2 * (size_t)BB * LL * CC + (size_t)b * LL * CC;
    float4 a;
    a.x = cbv[c4]; a.y = cbv[c4 + 1]; a.z = cbv[c4 + 2]; a.w = cbv[c4 + 3];
    #pragma unroll
    for (int dy = -1; dy <= 1; ++dy) {
        const int y = hr + dy;
        if (y < 0 || y >= HH) continue;
        #pragma unroll
        for (int dx = -1; dx <= 1; ++dx) {
            const int x = wc + dx;
            if (x < 0 || x >= WSP) continue;
            const int ln = y * WWID + wi * WSP + x;
            const float4 v = *(const float4*)(vp + (size_t)ln * CC + c4);
            const int widx = (dy + 1) * 3 + (dx + 1);
            a.x += cw[(c4 + 0) * 9 + widx] * v.x;
            a.y += cw[(c4 + 1) * 9 + widx] * v.y;
            a.z += cw[(c4 + 2) * 9 + widx] * v.z;
            a.w += cw[(c4 + 3) * 9 + widx] * v.w;
        }
    }
    float* op = out + (size_t)rest * CC + c4;
    float4 cur = *(const float4*)op;
    cur.x += a.x; cur.y += a.y; cur.z += a.z; cur.w += a.w;
    *(float4*)op = cur;
}

extern "C" void kernel_launch(void* const* d_in, const int* in_sizes, int n_in,
                              void* d_out, int out_size, void* d_ws, size_t ws_size,
                              hipStream_t stream) {
    const float* qkv = (const float*)d_in[0];
    const float* cw  = (const float*)d_in[1];
    const float* cb  = (const float*)d_in[2];
    float* out = (float*)d_out;

    dim3 grid(NQT, 256);
    attn_mfma<<<grid, 256, 0, stream>>>(qkv, out);

    const int total4 = BB * LL * (CC / 4);
    lepe2<<<(total4 + 255) / 256, 256, 0, stream>>>(qkv, cw, cb, out);
}